// Round 1
// baseline (1340.424 us; speedup 1.0000x reference)
//
#include <hip/hip_runtime.h>
#include <math.h>

#define B_   2
#define L_   1024
#define DM   1024
#define DS   16
#define DC   4
#define DI   2048          // E*DM
#define DR   64            // DM/16
#define NTOK (B_*L_)       // 2048
#define EPSF 1e-5f

__device__ __forceinline__ float siluf(float x){ return x / (1.f + __expf(-x)); }
__device__ __forceinline__ float softplusf(float x){ return (x > 20.f) ? x : log1pf(__expf(x)); }

// ---------------- RMSNorm: u = x * rsqrt(mean(x^2)+eps) * w ----------------
__global__ __launch_bounds__(256) void rmsnorm_k(const float* __restrict__ x,
                                                 const float* __restrict__ w,
                                                 float* __restrict__ u)
{
    int row = blockIdx.x;                       // token
    int t = threadIdx.x;
    float4 v = ((const float4*)(x + (size_t)row*DM))[t];
    float ss = v.x*v.x + v.y*v.y + v.z*v.z + v.w*v.w;
    #pragma unroll
    for (int off = 32; off > 0; off >>= 1) ss += __shfl_xor(ss, off, 64);
    __shared__ float sred[4];
    if ((t & 63) == 0) sred[t >> 6] = ss;
    __syncthreads();
    ss = sred[0] + sred[1] + sred[2] + sred[3];
    float rs = rsqrtf(ss * (1.f/(float)DM) + EPSF);
    float4 wv = ((const float4*)w)[t];
    float4 o;
    o.x = v.x*rs*wv.x; o.y = v.y*rs*wv.y; o.z = v.z*rs*wv.z; o.w = v.w*rs*wv.w;
    ((float4*)(u + (size_t)row*DM))[t] = o;
}

// ---------------- Generic NT GEMM: C[M,N] = A[M,K] * B[N,K]^T --------------
// EPI: 0 = plain, 1 = softplus(acc + bias[col]), 2 = acc + res[row,col]
template<int EPI>
__global__ __launch_bounds__(256) void gemm_nt(
    const float* __restrict__ A, int lda,
    const float* __restrict__ Bm, int ldb,
    float* __restrict__ C, int ldc,
    int M, int N, int K,
    const float* __restrict__ bias,
    const float* __restrict__ res)
{
    __shared__ float As[16][64];
    __shared__ float Bs[16][64];
    int t  = threadIdx.x;
    int tx = t & 15, ty = t >> 4;
    int m0 = blockIdx.y * 64, n0 = blockIdx.x * 64;
    int lr = t >> 2;            // 0..63 : row within tile for loading
    int lc = (t & 3) * 4;       // 0,4,8,12 : k-offset within tile

    float acc[4][4] = {};

    for (int k0 = 0; k0 < K; k0 += 16) {
        float4 av = {0,0,0,0}, bv = {0,0,0,0};
        if (m0 + lr < M) av = *(const float4*)(A  + (size_t)(m0+lr)*lda + k0 + lc);
        if (n0 + lr < N) bv = *(const float4*)(Bm + (size_t)(n0+lr)*ldb + k0 + lc);
        __syncthreads();
        As[lc+0][lr]=av.x; As[lc+1][lr]=av.y; As[lc+2][lr]=av.z; As[lc+3][lr]=av.w;
        Bs[lc+0][lr]=bv.x; Bs[lc+1][lr]=bv.y; Bs[lc+2][lr]=bv.z; Bs[lc+3][lr]=bv.w;
        __syncthreads();
        #pragma unroll
        for (int kk = 0; kk < 16; ++kk) {
            float4 a4 = *(const float4*)&As[kk][ty*4];
            float4 b4 = *(const float4*)&Bs[kk][tx*4];
            float ar[4] = {a4.x, a4.y, a4.z, a4.w};
            float br[4] = {b4.x, b4.y, b4.z, b4.w};
            #pragma unroll
            for (int i = 0; i < 4; ++i)
                #pragma unroll
                for (int j = 0; j < 4; ++j)
                    acc[i][j] = fmaf(ar[i], br[j], acc[i][j]);
        }
    }

    int row0 = m0 + ty*4, col0 = n0 + tx*4;
    if (col0 >= N) return;
    float4 bias4 = {0,0,0,0};
    if (EPI == 1) bias4 = *(const float4*)(bias + col0);
    #pragma unroll
    for (int i = 0; i < 4; ++i) {
        int r = row0 + i;
        if (r >= M) continue;
        float4 o; o.x = acc[i][0]; o.y = acc[i][1]; o.z = acc[i][2]; o.w = acc[i][3];
        if (EPI == 1) {
            o.x = softplusf(o.x + bias4.x); o.y = softplusf(o.y + bias4.y);
            o.z = softplusf(o.z + bias4.z); o.w = softplusf(o.w + bias4.w);
        } else if (EPI == 2) {
            float4 rv = *(const float4*)(res + (size_t)r*ldc + col0);
            o.x += rv.x; o.y += rv.y; o.z += rv.z; o.w += rv.w;
        }
        *(float4*)(C + (size_t)r*ldc + col0) = o;
    }
}

// ------------- causal depthwise conv (DC=4) + bias + SiLU ------------------
// xin = xz[:, 0:DI] (row stride 2*DI), out xc[NTOK, DI]
__global__ __launch_bounds__(256) void conv_silu_k(const float* __restrict__ xz,
                                                   const float* __restrict__ cw,
                                                   const float* __restrict__ cb,
                                                   float* __restrict__ xc)
{
    int idx = blockIdx.x * 256 + threadIdx.x;   // (token)*(DI/4) + d4
    int d4 = idx & (DI/4 - 1);
    int m  = idx >> 9;                          // DI/4 = 512
    int l  = m & (L_ - 1);
    int d  = d4 * 4;

    float4 w0 = *(const float4*)(cw + (size_t)(d+0)*DC);
    float4 w1 = *(const float4*)(cw + (size_t)(d+1)*DC);
    float4 w2 = *(const float4*)(cw + (size_t)(d+2)*DC);
    float4 w3 = *(const float4*)(cw + (size_t)(d+3)*DC);
    float wr0[4] = {w0.x,w0.y,w0.z,w0.w};
    float wr1[4] = {w1.x,w1.y,w1.z,w1.w};
    float wr2[4] = {w2.x,w2.y,w2.z,w2.w};
    float wr3[4] = {w3.x,w3.y,w3.z,w3.w};
    float4 bias = *(const float4*)(cb + d);
    float a0 = bias.x, a1 = bias.y, a2 = bias.z, a3 = bias.w;

    #pragma unroll
    for (int j = 0; j < DC; ++j) {
        int tt = l - (DC-1) + j;
        if (tt < 0) continue;
        float4 xv = *(const float4*)(xz + (size_t)(m - l + tt)*(2*DI) + d);
        a0 = fmaf(wr0[j], xv.x, a0);
        a1 = fmaf(wr1[j], xv.y, a1);
        a2 = fmaf(wr2[j], xv.z, a2);
        a3 = fmaf(wr3[j], xv.w, a3);
    }
    float4 o = { siluf(a0), siluf(a1), siluf(a2), siluf(a3) };
    *(float4*)(xc + (size_t)m*DI + d) = o;
}

// ---------------- selective scan + D-skip + gate ---------------------------
// thread layout: 16 lanes per channel (one per state n), 16 channels/block
// g may alias delta (same-index read happens before write within the wave)
__global__ __launch_bounds__(256) void scan_k(const float* delta,     // [NTOK,DI]
                                              const float* __restrict__ xz,    // [NTOK,2*DI]
                                              const float* __restrict__ xc,    // [NTOK,DI]
                                              const float* __restrict__ dbl,   // [NTOK,96]
                                              const float* __restrict__ A_log, // [DI,DS]
                                              const float* __restrict__ Dp,    // [DI]
                                              float* g)               // [NTOK,DI]
{
    int t  = threadIdx.x;
    int n  = t & 15;
    int dl = t >> 4;                       // 0..15
    int grp = blockIdx.x;                  // 0..255
    int b   = grp >> 7;                    // grp / (DI/16)
    int d   = (grp & 127) * 16 + dl;

    float Areg = -__expf(A_log[(size_t)d*DS + n]);
    float Dreg = Dp[d];
    float h = 0.f;
    int base = b * L_;

    for (int l = 0; l < L_; ++l) {
        int m = base + l;
        float dv = delta[(size_t)m*DI + d];
        float xv = xc[(size_t)m*DI + d];
        float bv = dbl[(size_t)m*96 + DR + n];
        float cv = dbl[(size_t)m*96 + DR + DS + n];
        float dA = __expf(dv * Areg);
        h = fmaf(dA, h, dv * bv * xv);
        float p = h * cv;
        p += __shfl_xor(p, 1, 16);
        p += __shfl_xor(p, 2, 16);
        p += __shfl_xor(p, 4, 16);
        p += __shfl_xor(p, 8, 16);
        if (n == 0) {
            float y  = p + xv * Dreg;
            float zv = xz[(size_t)m*(2*DI) + DI + d];
            g[(size_t)m*DI + d] = y * siluf(zv);
        }
    }
}

extern "C" void kernel_launch(void* const* d_in, const int* in_sizes, int n_in,
                              void* d_out, int out_size, void* d_ws, size_t ws_size,
                              hipStream_t stream)
{
    const float* x         = (const float*)d_in[0];
    const float* norm_w    = (const float*)d_in[1];
    const float* in_proj_w = (const float*)d_in[2];
    const float* conv_w    = (const float*)d_in[3];
    const float* conv_b    = (const float*)d_in[4];
    const float* x_proj_w  = (const float*)d_in[5];
    const float* dt_proj_w = (const float*)d_in[6];
    const float* dt_proj_b = (const float*)d_in[7];
    const float* A_log     = (const float*)d_in[8];
    const float* Dp        = (const float*)d_in[9];
    const float* out_proj_w= (const float*)d_in[10];
    float* out = (float*)d_out;

    char* p = (char*)d_ws;
    float* xz    = (float*)p; p += (size_t)NTOK*2*DI*4;   // 32 MB
    float* xc    = (float*)p; p += (size_t)NTOK*DI*4;     // 16 MB
    float* delta = (float*)p; p += (size_t)NTOK*DI*4;     // 16 MB
    float* u     = (float*)p; p += (size_t)NTOK*DM*4;     //  8 MB
    float* dbl   = (float*)p; p += (size_t)NTOK*96*4;     // .75 MB
    float* g     = delta;  // alias: same-index read-before-write in scan_k

    // 1. RMSNorm
    rmsnorm_k<<<NTOK, 256, 0, stream>>>(x, norm_w, u);

    // 2. in_proj: xz[NTOK, 2*DI] = u @ in_proj_w^T
    gemm_nt<0><<<dim3((2*DI)/64, NTOK/64), 256, 0, stream>>>(
        u, DM, in_proj_w, DM, xz, 2*DI, NTOK, 2*DI, DM, nullptr, nullptr);

    // 3. causal depthwise conv + SiLU: xc = silu(conv(xin)+b)
    conv_silu_k<<<(NTOK*(DI/4))/256, 256, 0, stream>>>(xz, conv_w, conv_b, xc);

    // 4. x_proj: dbl[NTOK, 96] = xc @ x_proj_w^T
    gemm_nt<0><<<dim3(2, NTOK/64), 256, 0, stream>>>(
        xc, DI, x_proj_w, DI, dbl, 96, NTOK, 96, DI, nullptr, nullptr);

    // 5. dt_proj + softplus: delta[NTOK, DI] = softplus(dbl[:, :64] @ dt_proj_w^T + b)
    gemm_nt<1><<<dim3(DI/64, NTOK/64), 256, 0, stream>>>(
        dbl, 96, dt_proj_w, DR, delta, DI, NTOK, DI, DR, dt_proj_b, nullptr);

    // 6. selective scan + D skip + gate: g = (scan_y + xc*D) * silu(z)
    scan_k<<<B_*(DI/16), 256, 0, stream>>>(delta, xz, xc, dbl, A_log, Dp, g);

    // 7. out_proj + residual: out = g @ out_proj_w^T + x
    gemm_nt<2><<<dim3(DM/64, NTOK/64), 256, 0, stream>>>(
        g, DI, out_proj_w, DI, out, DM, NTOK, DM, DI, nullptr, x);
}

// Round 2
// 760.965 us; speedup vs baseline: 1.7615x; 1.7615x over previous
//
#include <hip/hip_runtime.h>
#include <math.h>

#define B_   2
#define L_   1024
#define DM   1024
#define DS   16
#define DC   4
#define DI   2048          // E*DM
#define DR   64            // DM/16
#define NTOK (B_*L_)       // 2048
#define EPSF 1e-5f
#define NC   16            // scan chunks
#define CL   (L_/NC)       // 64 steps per chunk

__device__ __forceinline__ float siluf(float x){ return x / (1.f + __expf(-x)); }
__device__ __forceinline__ float softplusf(float x){ return (x > 20.f) ? x : log1pf(__expf(x)); }

// ---------------- RMSNorm: u = x * rsqrt(mean(x^2)+eps) * w ----------------
__global__ __launch_bounds__(256) void rmsnorm_k(const float* __restrict__ x,
                                                 const float* __restrict__ w,
                                                 float* __restrict__ u)
{
    int row = blockIdx.x;
    int t = threadIdx.x;
    float4 v = ((const float4*)(x + (size_t)row*DM))[t];
    float ss = v.x*v.x + v.y*v.y + v.z*v.z + v.w*v.w;
    #pragma unroll
    for (int off = 32; off > 0; off >>= 1) ss += __shfl_xor(ss, off, 64);
    __shared__ float sred[4];
    if ((t & 63) == 0) sred[t >> 6] = ss;
    __syncthreads();
    ss = sred[0] + sred[1] + sred[2] + sred[3];
    float rs = rsqrtf(ss * (1.f/(float)DM) + EPSF);
    float4 wv = ((const float4*)w)[t];
    float4 o;
    o.x = v.x*rs*wv.x; o.y = v.y*rs*wv.y; o.z = v.z*rs*wv.z; o.w = v.w*rs*wv.w;
    ((float4*)(u + (size_t)row*DM))[t] = o;
}

// ------------- small NT GEMM (kept for x_proj, N=96) -----------------------
template<int EPI>
__global__ __launch_bounds__(256) void gemm_nt(
    const float* __restrict__ A, int lda,
    const float* __restrict__ Bm, int ldb,
    float* __restrict__ C, int ldc,
    int M, int N, int K,
    const float* __restrict__ bias,
    const float* __restrict__ res)
{
    __shared__ float As[16][64];
    __shared__ float Bs[16][64];
    int t  = threadIdx.x;
    int tx = t & 15, ty = t >> 4;
    int m0 = blockIdx.y * 64, n0 = blockIdx.x * 64;
    int lr = t >> 2;
    int lc = (t & 3) * 4;

    float acc[4][4] = {};

    for (int k0 = 0; k0 < K; k0 += 16) {
        float4 av = {0,0,0,0}, bv = {0,0,0,0};
        if (m0 + lr < M) av = *(const float4*)(A  + (size_t)(m0+lr)*lda + k0 + lc);
        if (n0 + lr < N) bv = *(const float4*)(Bm + (size_t)(n0+lr)*ldb + k0 + lc);
        __syncthreads();
        As[lc+0][lr]=av.x; As[lc+1][lr]=av.y; As[lc+2][lr]=av.z; As[lc+3][lr]=av.w;
        Bs[lc+0][lr]=bv.x; Bs[lc+1][lr]=bv.y; Bs[lc+2][lr]=bv.z; Bs[lc+3][lr]=bv.w;
        __syncthreads();
        #pragma unroll
        for (int kk = 0; kk < 16; ++kk) {
            float4 a4 = *(const float4*)&As[kk][ty*4];
            float4 b4 = *(const float4*)&Bs[kk][tx*4];
            float ar[4] = {a4.x, a4.y, a4.z, a4.w};
            float br[4] = {b4.x, b4.y, b4.z, b4.w};
            #pragma unroll
            for (int i = 0; i < 4; ++i)
                #pragma unroll
                for (int j = 0; j < 4; ++j)
                    acc[i][j] = fmaf(ar[i], br[j], acc[i][j]);
        }
    }

    int row0 = m0 + ty*4, col0 = n0 + tx*4;
    if (col0 >= N) return;
    float4 bias4 = {0,0,0,0};
    if (EPI == 1) bias4 = *(const float4*)(bias + col0);
    #pragma unroll
    for (int i = 0; i < 4; ++i) {
        int r = row0 + i;
        if (r >= M) continue;
        float4 o; o.x = acc[i][0]; o.y = acc[i][1]; o.z = acc[i][2]; o.w = acc[i][3];
        if (EPI == 1) {
            o.x = softplusf(o.x + bias4.x); o.y = softplusf(o.y + bias4.y);
            o.z = softplusf(o.z + bias4.z); o.w = softplusf(o.w + bias4.w);
        } else if (EPI == 2) {
            float4 rv = *(const float4*)(res + (size_t)r*ldc + col0);
            o.x += rv.x; o.y += rv.y; o.z += rv.z; o.w += rv.w;
        }
        *(float4*)(C + (size_t)r*ldc + col0) = o;
    }
}

// ------------- big NT GEMM: BM x 128 tile, 8x8 (or 4x8) acc ----------------
// requires M%BM==0, N%128==0, K%16==0. EPI: 0 plain, 1 softplus+bias, 2 +res
template<int BM, int EPI>
__global__ __launch_bounds__(256) void gemm_big(
    const float* __restrict__ A, int lda,
    const float* __restrict__ Bm, int ldb,
    float* __restrict__ C, int ldc,
    int M, int N, int K,
    const float* __restrict__ bias,
    const float* __restrict__ res)
{
    constexpr int NR = BM / 64;
    __shared__ float As[16][BM + 4];
    __shared__ float Bs[16][132];
    int t  = threadIdx.x;
    int tx = t & 15, ty = t >> 4;
    int m0 = blockIdx.y * BM, n0 = blockIdx.x * 128;
    int lr = t >> 2;
    int lc = (t & 3) * 4;

    float acc[NR][2][4][4] = {};

    for (int k0 = 0; k0 < K; k0 += 16) {
        float4 av[NR], bv[2];
        #pragma unroll
        for (int r = 0; r < NR; ++r)
            av[r] = *(const float4*)(A + (size_t)(m0+lr+64*r)*lda + k0 + lc);
        #pragma unroll
        for (int r = 0; r < 2; ++r)
            bv[r] = *(const float4*)(Bm + (size_t)(n0+lr+64*r)*ldb + k0 + lc);
        __syncthreads();
        #pragma unroll
        for (int r = 0; r < NR; ++r) {
            As[lc+0][lr+64*r]=av[r].x; As[lc+1][lr+64*r]=av[r].y;
            As[lc+2][lr+64*r]=av[r].z; As[lc+3][lr+64*r]=av[r].w;
        }
        #pragma unroll
        for (int r = 0; r < 2; ++r) {
            Bs[lc+0][lr+64*r]=bv[r].x; Bs[lc+1][lr+64*r]=bv[r].y;
            Bs[lc+2][lr+64*r]=bv[r].z; Bs[lc+3][lr+64*r]=bv[r].w;
        }
        __syncthreads();
        #pragma unroll
        for (int kk = 0; kk < 16; ++kk) {
            float a[NR][4], b[2][4];
            #pragma unroll
            for (int r = 0; r < NR; ++r)
                *(float4*)a[r] = *(const float4*)&As[kk][ty*4 + 64*r];
            #pragma unroll
            for (int r = 0; r < 2; ++r)
                *(float4*)b[r] = *(const float4*)&Bs[kk][tx*4 + 64*r];
            #pragma unroll
            for (int r = 0; r < NR; ++r)
                #pragma unroll
                for (int s = 0; s < 2; ++s)
                    #pragma unroll
                    for (int i = 0; i < 4; ++i)
                        #pragma unroll
                        for (int j = 0; j < 4; ++j)
                            acc[r][s][i][j] = fmaf(a[r][i], b[s][j], acc[r][s][i][j]);
        }
    }

    #pragma unroll
    for (int r = 0; r < NR; ++r) {
        #pragma unroll
        for (int s = 0; s < 2; ++s) {
            int col0 = n0 + tx*4 + 64*s;
            float4 bias4 = {0,0,0,0};
            if (EPI == 1) bias4 = *(const float4*)(bias + col0);
            #pragma unroll
            for (int i = 0; i < 4; ++i) {
                int row = m0 + ty*4 + 64*r + i;
                float4 o = {acc[r][s][i][0], acc[r][s][i][1],
                            acc[r][s][i][2], acc[r][s][i][3]};
                if (EPI == 1) {
                    o.x = softplusf(o.x + bias4.x); o.y = softplusf(o.y + bias4.y);
                    o.z = softplusf(o.z + bias4.z); o.w = softplusf(o.w + bias4.w);
                } else if (EPI == 2) {
                    float4 rv = *(const float4*)(res + (size_t)row*ldc + col0);
                    o.x += rv.x; o.y += rv.y; o.z += rv.z; o.w += rv.w;
                }
                *(float4*)(C + (size_t)row*ldc + col0) = o;
            }
        }
    }
}

// ------------- causal depthwise conv (DC=4) + bias + SiLU ------------------
__global__ __launch_bounds__(256) void conv_silu_k(const float* __restrict__ xz,
                                                   const float* __restrict__ cw,
                                                   const float* __restrict__ cb,
                                                   float* __restrict__ xc)
{
    int idx = blockIdx.x * 256 + threadIdx.x;
    int d4 = idx & (DI/4 - 1);
    int m  = idx >> 9;
    int l  = m & (L_ - 1);
    int d  = d4 * 4;

    float4 w0 = *(const float4*)(cw + (size_t)(d+0)*DC);
    float4 w1 = *(const float4*)(cw + (size_t)(d+1)*DC);
    float4 w2 = *(const float4*)(cw + (size_t)(d+2)*DC);
    float4 w3 = *(const float4*)(cw + (size_t)(d+3)*DC);
    float wr0[4] = {w0.x,w0.y,w0.z,w0.w};
    float wr1[4] = {w1.x,w1.y,w1.z,w1.w};
    float wr2[4] = {w2.x,w2.y,w2.z,w2.w};
    float wr3[4] = {w3.x,w3.y,w3.z,w3.w};
    float4 bias = *(const float4*)(cb + d);
    float a0 = bias.x, a1 = bias.y, a2 = bias.z, a3 = bias.w;

    #pragma unroll
    for (int j = 0; j < DC; ++j) {
        int tt = l - (DC-1) + j;
        if (tt < 0) continue;
        float4 xv = *(const float4*)(xz + (size_t)(m - l + tt)*(2*DI) + d);
        a0 = fmaf(wr0[j], xv.x, a0);
        a1 = fmaf(wr1[j], xv.y, a1);
        a2 = fmaf(wr2[j], xv.z, a2);
        a3 = fmaf(wr3[j], xv.w, a3);
    }
    float4 o = { siluf(a0), siluf(a1), siluf(a2), siluf(a3) };
    *(float4*)(xc + (size_t)m*DI + d) = o;
}

// ---------------- chunked selective scan ----------------------------------
// Phase 1: per (b, chunk, d): run chunk from h=0, keep all 16 states in regs.
// Store partial state H[16] and chunk decay P[n] = exp(A[n] * sum(delta)).
__global__ __launch_bounds__(256) void scan_p1(const float* __restrict__ delta,
                                               const float* __restrict__ xc,
                                               const float* __restrict__ dbl,
                                               const float* __restrict__ A_log,
                                               float* __restrict__ Pbuf,
                                               float* __restrict__ Hbuf)
{
    __shared__ float Bsh[CL][16];
    int t = threadIdx.x;
    int blk = blockIdx.x;                 // b*128 + c*8 + dblk
    int d = (blk & 7) * 256 + t;
    int c = (blk >> 3) & (NC - 1);
    int b = blk >> 7;
    int m0 = b * L_ + c * CL;

    for (int i = t; i < CL*16; i += 256)
        Bsh[i >> 4][i & 15] = dbl[(size_t)(m0 + (i >> 4))*96 + DR + (i & 15)];
    __syncthreads();

    float A[16], h[16];
    #pragma unroll
    for (int j = 0; j < 4; ++j) {
        float4 al = *(const float4*)(A_log + (size_t)d*DS + j*4);
        A[j*4+0] = -__expf(al.x); A[j*4+1] = -__expf(al.y);
        A[j*4+2] = -__expf(al.z); A[j*4+3] = -__expf(al.w);
    }
    #pragma unroll
    for (int n = 0; n < 16; ++n) h[n] = 0.f;
    float S = 0.f;

    #pragma unroll 4
    for (int tt = 0; tt < CL; ++tt) {
        int m = m0 + tt;
        float dv = delta[(size_t)m*DI + d];
        float xv = xc[(size_t)m*DI + d];
        float dx = dv * xv;
        S += dv;
        #pragma unroll
        for (int n = 0; n < 16; ++n) {
            float dA = __expf(dv * A[n]);
            h[n] = fmaf(dA, h[n], Bsh[tt][n] * dx);
        }
    }

    size_t o = ((size_t)((b*NC + c)*DI) + d) * DS;
    #pragma unroll
    for (int j = 0; j < 4; ++j) {
        float4 pv, hv;
        pv.x = __expf(A[j*4+0]*S); pv.y = __expf(A[j*4+1]*S);
        pv.z = __expf(A[j*4+2]*S); pv.w = __expf(A[j*4+3]*S);
        hv.x = h[j*4+0]; hv.y = h[j*4+1]; hv.z = h[j*4+2]; hv.w = h[j*4+3];
        *(float4*)(Pbuf + o + j*4) = pv;
        *(float4*)(Hbuf + o + j*4) = hv;
    }
}

// Phase 2: scan the NC chunk summaries per (b,d,n); writes h0 in place of P.
__global__ __launch_bounds__(256) void scan_p2(float* Pbuf, const float* __restrict__ Hbuf)
{
    int idx = blockIdx.x * 256 + threadIdx.x;   // (b, d, n)
    int n = idx & 15;
    int d = (idx >> 4) & (DI - 1);
    int b = idx >> 15;
    float h = 0.f;
    #pragma unroll
    for (int c = 0; c < NC; ++c) {
        size_t o = ((size_t)((b*NC + c)*DI) + d) * DS + n;
        float p  = Pbuf[o];
        float hh = Hbuf[o];
        Pbuf[o] = h;                 // h0 entering chunk c
        h = fmaf(p, h, hh);
    }
}

// Phase 3: replay chunk from h0, emit g = (y + xc*D) * silu(z).
// NOTE: g aliases delta -> no __restrict__ on those two; loads for each
// group of 4 steps are issued before the group's stores (manual pipeline).
__global__ __launch_bounds__(256) void scan_p3(const float* delta,
                                               const float* __restrict__ xz,
                                               const float* __restrict__ xc,
                                               const float* __restrict__ dbl,
                                               const float* __restrict__ A_log,
                                               const float* __restrict__ Dp,
                                               const float* __restrict__ h0buf,
                                               float* g)
{
    __shared__ float Bsh[CL][16];
    __shared__ float Csh[CL][16];
    int t = threadIdx.x;
    int blk = blockIdx.x;
    int d = (blk & 7) * 256 + t;
    int c = (blk >> 3) & (NC - 1);
    int b = blk >> 7;
    int m0 = b * L_ + c * CL;

    for (int i = t; i < CL*16; i += 256) {
        int tt = i >> 4, n = i & 15;
        size_t ro = (size_t)(m0 + tt)*96 + DR;
        Bsh[tt][n] = dbl[ro + n];
        Csh[tt][n] = dbl[ro + DS + n];
    }
    __syncthreads();

    float A[16], h[16];
    #pragma unroll
    for (int j = 0; j < 4; ++j) {
        float4 al = *(const float4*)(A_log + (size_t)d*DS + j*4);
        A[j*4+0] = -__expf(al.x); A[j*4+1] = -__expf(al.y);
        A[j*4+2] = -__expf(al.z); A[j*4+3] = -__expf(al.w);
    }
    size_t o = ((size_t)((b*NC + c)*DI) + d) * DS;
    #pragma unroll
    for (int j = 0; j < 4; ++j) {
        float4 hv = *(const float4*)(h0buf + o + j*4);
        h[j*4+0] = hv.x; h[j*4+1] = hv.y; h[j*4+2] = hv.z; h[j*4+3] = hv.w;
    }
    float Dreg = Dp[d];

    for (int t0 = 0; t0 < CL; t0 += 4) {
        float dv[4], xv[4], zv[4];
        #pragma unroll
        for (int q = 0; q < 4; ++q) {
            int m = m0 + t0 + q;
            dv[q] = delta[(size_t)m*DI + d];
            xv[q] = xc[(size_t)m*DI + d];
            zv[q] = xz[(size_t)m*(2*DI) + DI + d];
        }
        #pragma unroll
        for (int q = 0; q < 4; ++q) {
            int tt = t0 + q, m = m0 + tt;
            float dx = dv[q] * xv[q];
            float y = 0.f;
            #pragma unroll
            for (int n = 0; n < 16; ++n) {
                float dA = __expf(dv[q] * A[n]);
                h[n] = fmaf(dA, h[n], Bsh[tt][n] * dx);
                y = fmaf(h[n], Csh[tt][n], y);
            }
            g[(size_t)m*DI + d] = (y + xv[q]*Dreg) * siluf(zv[q]);
        }
    }
}

extern "C" void kernel_launch(void* const* d_in, const int* in_sizes, int n_in,
                              void* d_out, int out_size, void* d_ws, size_t ws_size,
                              hipStream_t stream)
{
    const float* x         = (const float*)d_in[0];
    const float* norm_w    = (const float*)d_in[1];
    const float* in_proj_w = (const float*)d_in[2];
    const float* conv_w    = (const float*)d_in[3];
    const float* conv_b    = (const float*)d_in[4];
    const float* x_proj_w  = (const float*)d_in[5];
    const float* dt_proj_w = (const float*)d_in[6];
    const float* dt_proj_b = (const float*)d_in[7];
    const float* A_log     = (const float*)d_in[8];
    const float* Dp        = (const float*)d_in[9];
    const float* out_proj_w= (const float*)d_in[10];
    float* out = (float*)d_out;

    char* p = (char*)d_ws;
    float* xz    = (float*)p; p += (size_t)NTOK*2*DI*4;   // 33.6 MB
    float* xc    = (float*)p; p += (size_t)NTOK*DI*4;     // 16.8 MB
    float* delta = (float*)p; p += (size_t)NTOK*DI*4;     // 16.8 MB
    float* u     = (float*)p; p += (size_t)NTOK*DM*4;     //  8.4 MB
    float* dbl   = (float*)p; p += (size_t)NTOK*96*4;     //  0.8 MB
    float* Hbuf  = (float*)p; p += (size_t)B_*NC*DI*DS*4; //  8.4 MB
    float* Pbuf  = u;      // u dead after in_proj; same size (8.4 MB)
    float* g     = delta;  // alias: per-element read-before-write in scan_p3

    // 1. RMSNorm
    rmsnorm_k<<<NTOK, 256, 0, stream>>>(x, norm_w, u);

    // 2. in_proj: xz[NTOK, 2*DI] = u @ in_proj_w^T
    gemm_big<128,0><<<dim3((2*DI)/128, NTOK/128), 256, 0, stream>>>(
        u, DM, in_proj_w, DM, xz, 2*DI, NTOK, 2*DI, DM, nullptr, nullptr);

    // 3. causal depthwise conv + SiLU
    conv_silu_k<<<(NTOK*(DI/4))/256, 256, 0, stream>>>(xz, conv_w, conv_b, xc);

    // 4. x_proj: dbl[NTOK, 96] = xc @ x_proj_w^T
    gemm_nt<0><<<dim3(2, NTOK/64), 256, 0, stream>>>(
        xc, DI, x_proj_w, DI, dbl, 96, NTOK, 96, DI, nullptr, nullptr);

    // 5. dt_proj + softplus: delta = softplus(dbl[:, :64] @ dt_proj_w^T + b)
    gemm_big<128,1><<<dim3(DI/128, NTOK/128), 256, 0, stream>>>(
        dbl, 96, dt_proj_w, DR, delta, DI, NTOK, DI, DR, dt_proj_b, nullptr);

    // 6. chunked selective scan
    scan_p1<<<B_*NC*(DI/256), 256, 0, stream>>>(delta, xc, dbl, A_log, Pbuf, Hbuf);
    scan_p2<<<(B_*DI*DS)/256, 256, 0, stream>>>(Pbuf, Hbuf);
    scan_p3<<<B_*NC*(DI/256), 256, 0, stream>>>(delta, xz, xc, dbl, A_log, Dp,
                                                Pbuf, g);

    // 7. out_proj + residual: out = g @ out_proj_w^T + x
    gemm_big<64,2><<<dim3(DM/128, NTOK/64), 256, 0, stream>>>(
        g, DI, out_proj_w, DI, out, DM, NTOK, DM, DI, nullptr, x);
}

// Round 3
// 543.245 us; speedup vs baseline: 2.4674x; 1.4008x over previous
//
#include <hip/hip_runtime.h>
#include <math.h>

#define B_   2
#define L_   1024
#define DM   1024
#define DS   16
#define DC   4
#define DI   2048          // E*DM
#define DR   64            // DM/16
#define NTOK (B_*L_)       // 2048
#define EPSF 1e-5f
#define NC   16            // scan chunks
#define CL   (L_/NC)       // 64 steps per chunk

typedef __bf16 bf16_t;
typedef bf16_t bf16x4 __attribute__((ext_vector_type(4)));
typedef bf16_t bf16x8 __attribute__((ext_vector_type(8)));
typedef float  f32x4  __attribute__((ext_vector_type(4)));

__device__ __forceinline__ float siluf(float x){ return x / (1.f + __expf(-x)); }
__device__ __forceinline__ float softplusf(float x){ return (x > 20.f) ? x : log1pf(__expf(x)); }

__device__ __forceinline__ void gload_lds16(const void* g, void* l) {
    __builtin_amdgcn_global_load_lds(
        (const __attribute__((address_space(1))) void*)g,
        (__attribute__((address_space(3))) void*)l, 16, 0, 0);
}

// ---------------- RMSNorm -> split bf16 (hi, lo) ---------------------------
__global__ __launch_bounds__(256) void rmsnorm_k(const float* __restrict__ x,
                                                 const float* __restrict__ w,
                                                 bf16_t* __restrict__ uh,
                                                 bf16_t* __restrict__ ul)
{
    int row = blockIdx.x;
    int t = threadIdx.x;
    float4 v = ((const float4*)(x + (size_t)row*DM))[t];
    float ss = v.x*v.x + v.y*v.y + v.z*v.z + v.w*v.w;
    #pragma unroll
    for (int off = 32; off > 0; off >>= 1) ss += __shfl_xor(ss, off, 64);
    __shared__ float sred[4];
    if ((t & 63) == 0) sred[t >> 6] = ss;
    __syncthreads();
    ss = sred[0] + sred[1] + sred[2] + sred[3];
    float rs = rsqrtf(ss * (1.f/(float)DM) + EPSF);
    float4 wv = ((const float4*)w)[t];
    float o[4];
    o[0] = v.x*rs*wv.x; o[1] = v.y*rs*wv.y; o[2] = v.z*rs*wv.z; o[3] = v.w*rs*wv.w;
    bf16x4 hv, lv;
    #pragma unroll
    for (int j = 0; j < 4; ++j) {
        bf16_t h = (bf16_t)o[j];
        hv[j] = h;
        lv[j] = (bf16_t)(o[j] - (float)h);
    }
    *(bf16x4*)(uh + (size_t)row*DM + t*4) = hv;
    *(bf16x4*)(ul + (size_t)row*DM + t*4) = lv;
}

// ---------------- fp32 -> split bf16 (hi, lo) ------------------------------
__global__ __launch_bounds__(256) void split_k(const float* __restrict__ s,
                                               bf16_t* __restrict__ h,
                                               bf16_t* __restrict__ l, int n4)
{
    int i = blockIdx.x * 256 + threadIdx.x;
    if (i >= n4) return;
    float4 v = ((const float4*)s)[i];
    float o[4] = {v.x, v.y, v.z, v.w};
    bf16x4 hv, lv;
    #pragma unroll
    for (int j = 0; j < 4; ++j) {
        bf16_t hh = (bf16_t)o[j];
        hv[j] = hh;
        lv[j] = (bf16_t)(o[j] - (float)hh);
    }
    ((bf16x4*)h)[i] = hv;
    ((bf16x4*)l)[i] = lv;
}

// ---------------- split-bf16 MFMA NT GEMM ----------------------------------
// C[M,N] (fp32) = (Ah+Al)[M,K] * (Bh+Bl)[N,K]^T, 3 MFMAs per product term.
// Tile 128 x BN, 256 threads = 4 waves (2x2). EPI: 0 plain, 2 += res.
template<int BN, int EPI>
__global__ __launch_bounds__(256) void gemm_mfma(
    const bf16_t* __restrict__ Ah, const bf16_t* __restrict__ Al,
    const bf16_t* __restrict__ Bh, const bf16_t* __restrict__ Bl,
    float* __restrict__ C, int ldc,
    const float* __restrict__ res,
    int M, int N, int K)
{
    constexpr int NJ   = BN / 32;        // B fragments per wave (n-dir)
    constexpr int WN   = BN / 2;         // wave n-span
    constexpr int ACH  = 8;              // 1KB chunks per A tile (128x32)
    constexpr int BCH  = BN / 16;        // 1KB chunks per B tile (BNx32)
    constexpr int NCH  = 2*ACH + 2*BCH;
    constexpr int PERW = NCH / 4;
    constexpr int AOFF_L = 128*32;           // elems
    constexpr int BOFF_H = 2*128*32;
    constexpr int BOFF_L = 2*128*32 + BN*32;

    __shared__ bf16_t lds[2*128*32 + 2*BN*32];

    int t = threadIdx.x;
    int w = t >> 6, lane = t & 63;
    int wr = w >> 1, wc = w & 1;
    int m0 = blockIdx.y * 128, n0 = blockIdx.x * BN;

    f32x4 acc[4][NJ];
    #pragma unroll
    for (int i = 0; i < 4; ++i)
        #pragma unroll
        for (int j = 0; j < NJ; ++j)
            acc[i][j] = (f32x4){0.f, 0.f, 0.f, 0.f};

    int lrow = lane >> 2;          // 0..15 within chunk
    int lcol = (lane & 3) * 8;     // k element offset
    int ar   = wr*64 + (lane & 15);
    int br   = wc*WN + (lane & 15);
    int koff = (lane >> 4) * 8;

    for (int k0 = 0; k0 < K; k0 += 32) {
        // ---- stage 4 tiles (Ah,Al,Bh,Bl)[*][32] via global_load_lds ----
        #pragma unroll
        for (int q = 0; q < PERW; ++q) {
            int ch = w * PERW + q;
            const bf16_t* g; int le;
            if (ch < ACH) {
                int cc = ch;
                g  = Ah + (size_t)(m0 + cc*16 + lrow)*K + k0 + lcol;
                le = cc*512 + lane*8;
            } else if (ch < 2*ACH) {
                int cc = ch - ACH;
                g  = Al + (size_t)(m0 + cc*16 + lrow)*K + k0 + lcol;
                le = AOFF_L + cc*512 + lane*8;
            } else if (ch < 2*ACH + BCH) {
                int cc = ch - 2*ACH;
                g  = Bh + (size_t)(n0 + cc*16 + lrow)*K + k0 + lcol;
                le = BOFF_H + cc*512 + lane*8;
            } else {
                int cc = ch - 2*ACH - BCH;
                g  = Bl + (size_t)(n0 + cc*16 + lrow)*K + k0 + lcol;
                le = BOFF_L + cc*512 + lane*8;
            }
            gload_lds16(g, &lds[le]);
        }
        __syncthreads();   // drains vmcnt (global_load_lds) + lgkm

        bf16x8 ah[4], al[4], bh[NJ], bl[NJ];
        #pragma unroll
        for (int i = 0; i < 4; ++i) {
            ah[i] = *(const bf16x8*)&lds[(ar + i*16)*32 + koff];
            al[i] = *(const bf16x8*)&lds[AOFF_L + (ar + i*16)*32 + koff];
        }
        #pragma unroll
        for (int j = 0; j < NJ; ++j) {
            bh[j] = *(const bf16x8*)&lds[BOFF_H + (br + j*16)*32 + koff];
            bl[j] = *(const bf16x8*)&lds[BOFF_L + (br + j*16)*32 + koff];
        }
        #pragma unroll
        for (int i = 0; i < 4; ++i)
            #pragma unroll
            for (int j = 0; j < NJ; ++j) {
                acc[i][j] = __builtin_amdgcn_mfma_f32_16x16x32_bf16(ah[i], bh[j], acc[i][j], 0, 0, 0);
                acc[i][j] = __builtin_amdgcn_mfma_f32_16x16x32_bf16(al[i], bh[j], acc[i][j], 0, 0, 0);
                acc[i][j] = __builtin_amdgcn_mfma_f32_16x16x32_bf16(ah[i], bl[j], acc[i][j], 0, 0, 0);
            }
        __syncthreads();   // protect lds before next stage
    }

    // epilogue: C/D layout col=lane&15, row=(lane>>4)*4+reg  [m89-verified]
    int rb = m0 + wr*64 + (lane >> 4)*4;
    int cb = n0 + wc*WN + (lane & 15);
    #pragma unroll
    for (int i = 0; i < 4; ++i)
        #pragma unroll
        for (int j = 0; j < NJ; ++j) {
            int col = cb + j*16;
            #pragma unroll
            for (int r = 0; r < 4; ++r) {
                int row = rb + i*16 + r;
                float v = acc[i][j][r];
                if (EPI == 2) v += res[(size_t)row*ldc + col];
                C[(size_t)row*ldc + col] = v;
            }
        }
}

// ------------- small NT GEMM (x_proj, N=96) --------------------------------
template<int EPI>
__global__ __launch_bounds__(256) void gemm_nt(
    const float* __restrict__ A, int lda,
    const float* __restrict__ Bm, int ldb,
    float* __restrict__ C, int ldc,
    int M, int N, int K,
    const float* __restrict__ bias,
    const float* __restrict__ res)
{
    __shared__ float As[16][64];
    __shared__ float Bs[16][64];
    int t  = threadIdx.x;
    int tx = t & 15, ty = t >> 4;
    int m0 = blockIdx.y * 64, n0 = blockIdx.x * 64;
    int lr = t >> 2;
    int lc = (t & 3) * 4;

    float acc[4][4] = {};

    for (int k0 = 0; k0 < K; k0 += 16) {
        float4 av = {0,0,0,0}, bv = {0,0,0,0};
        if (m0 + lr < M) av = *(const float4*)(A  + (size_t)(m0+lr)*lda + k0 + lc);
        if (n0 + lr < N) bv = *(const float4*)(Bm + (size_t)(n0+lr)*ldb + k0 + lc);
        __syncthreads();
        As[lc+0][lr]=av.x; As[lc+1][lr]=av.y; As[lc+2][lr]=av.z; As[lc+3][lr]=av.w;
        Bs[lc+0][lr]=bv.x; Bs[lc+1][lr]=bv.y; Bs[lc+2][lr]=bv.z; Bs[lc+3][lr]=bv.w;
        __syncthreads();
        #pragma unroll
        for (int kk = 0; kk < 16; ++kk) {
            float4 a4 = *(const float4*)&As[kk][ty*4];
            float4 b4 = *(const float4*)&Bs[kk][tx*4];
            float ar[4] = {a4.x, a4.y, a4.z, a4.w};
            float br[4] = {b4.x, b4.y, b4.z, b4.w};
            #pragma unroll
            for (int i = 0; i < 4; ++i)
                #pragma unroll
                for (int j = 0; j < 4; ++j)
                    acc[i][j] = fmaf(ar[i], br[j], acc[i][j]);
        }
    }

    int row0 = m0 + ty*4, col0 = n0 + tx*4;
    if (col0 >= N) return;
    float4 bias4 = {0,0,0,0};
    if (EPI == 1) bias4 = *(const float4*)(bias + col0);
    #pragma unroll
    for (int i = 0; i < 4; ++i) {
        int r = row0 + i;
        if (r >= M) continue;
        float4 o; o.x = acc[i][0]; o.y = acc[i][1]; o.z = acc[i][2]; o.w = acc[i][3];
        if (EPI == 1) {
            o.x = softplusf(o.x + bias4.x); o.y = softplusf(o.y + bias4.y);
            o.z = softplusf(o.z + bias4.z); o.w = softplusf(o.w + bias4.w);
        } else if (EPI == 2) {
            float4 rv = *(const float4*)(res + (size_t)r*ldc + col0);
            o.x += rv.x; o.y += rv.y; o.z += rv.z; o.w += rv.w;
        }
        *(float4*)(C + (size_t)r*ldc + col0) = o;
    }
}

// ------------- big fp32 NT GEMM (dt_proj, K=64) ----------------------------
template<int BM, int EPI>
__global__ __launch_bounds__(256) void gemm_big(
    const float* __restrict__ A, int lda,
    const float* __restrict__ Bm, int ldb,
    float* __restrict__ C, int ldc,
    int M, int N, int K,
    const float* __restrict__ bias,
    const float* __restrict__ res)
{
    constexpr int NR = BM / 64;
    __shared__ float As[16][BM + 4];
    __shared__ float Bs[16][132];
    int t  = threadIdx.x;
    int tx = t & 15, ty = t >> 4;
    int m0 = blockIdx.y * BM, n0 = blockIdx.x * 128;
    int lr = t >> 2;
    int lc = (t & 3) * 4;

    float acc[NR][2][4][4] = {};

    for (int k0 = 0; k0 < K; k0 += 16) {
        float4 av[NR], bv[2];
        #pragma unroll
        for (int r = 0; r < NR; ++r)
            av[r] = *(const float4*)(A + (size_t)(m0+lr+64*r)*lda + k0 + lc);
        #pragma unroll
        for (int r = 0; r < 2; ++r)
            bv[r] = *(const float4*)(Bm + (size_t)(n0+lr+64*r)*ldb + k0 + lc);
        __syncthreads();
        #pragma unroll
        for (int r = 0; r < NR; ++r) {
            As[lc+0][lr+64*r]=av[r].x; As[lc+1][lr+64*r]=av[r].y;
            As[lc+2][lr+64*r]=av[r].z; As[lc+3][lr+64*r]=av[r].w;
        }
        #pragma unroll
        for (int r = 0; r < 2; ++r) {
            Bs[lc+0][lr+64*r]=bv[r].x; Bs[lc+1][lr+64*r]=bv[r].y;
            Bs[lc+2][lr+64*r]=bv[r].z; Bs[lc+3][lr+64*r]=bv[r].w;
        }
        __syncthreads();
        #pragma unroll
        for (int kk = 0; kk < 16; ++kk) {
            float a[NR][4], b[2][4];
            #pragma unroll
            for (int r = 0; r < NR; ++r)
                *(float4*)a[r] = *(const float4*)&As[kk][ty*4 + 64*r];
            #pragma unroll
            for (int r = 0; r < 2; ++r)
                *(float4*)b[r] = *(const float4*)&Bs[kk][tx*4 + 64*r];
            #pragma unroll
            for (int r = 0; r < NR; ++r)
                #pragma unroll
                for (int s = 0; s < 2; ++s)
                    #pragma unroll
                    for (int i = 0; i < 4; ++i)
                        #pragma unroll
                        for (int j = 0; j < 4; ++j)
                            acc[r][s][i][j] = fmaf(a[r][i], b[s][j], acc[r][s][i][j]);
        }
    }

    #pragma unroll
    for (int r = 0; r < NR; ++r) {
        #pragma unroll
        for (int s = 0; s < 2; ++s) {
            int col0 = n0 + tx*4 + 64*s;
            float4 bias4 = {0,0,0,0};
            if (EPI == 1) bias4 = *(const float4*)(bias + col0);
            #pragma unroll
            for (int i = 0; i < 4; ++i) {
                int row = m0 + ty*4 + 64*r + i;
                float4 o = {acc[r][s][i][0], acc[r][s][i][1],
                            acc[r][s][i][2], acc[r][s][i][3]};
                if (EPI == 1) {
                    o.x = softplusf(o.x + bias4.x); o.y = softplusf(o.y + bias4.y);
                    o.z = softplusf(o.z + bias4.z); o.w = softplusf(o.w + bias4.w);
                } else if (EPI == 2) {
                    float4 rv = *(const float4*)(res + (size_t)row*ldc + col0);
                    o.x += rv.x; o.y += rv.y; o.z += rv.z; o.w += rv.w;
                }
                *(float4*)(C + (size_t)row*ldc + col0) = o;
            }
        }
    }
}

// ------------- causal depthwise conv (DC=4) + bias + SiLU ------------------
__global__ __launch_bounds__(256) void conv_silu_k(const float* __restrict__ xz,
                                                   const float* __restrict__ cw,
                                                   const float* __restrict__ cb,
                                                   float* __restrict__ xc)
{
    int idx = blockIdx.x * 256 + threadIdx.x;
    int d4 = idx & (DI/4 - 1);
    int m  = idx >> 9;
    int l  = m & (L_ - 1);
    int d  = d4 * 4;

    float4 w0 = *(const float4*)(cw + (size_t)(d+0)*DC);
    float4 w1 = *(const float4*)(cw + (size_t)(d+1)*DC);
    float4 w2 = *(const float4*)(cw + (size_t)(d+2)*DC);
    float4 w3 = *(const float4*)(cw + (size_t)(d+3)*DC);
    float wr0[4] = {w0.x,w0.y,w0.z,w0.w};
    float wr1[4] = {w1.x,w1.y,w1.z,w1.w};
    float wr2[4] = {w2.x,w2.y,w2.z,w2.w};
    float wr3[4] = {w3.x,w3.y,w3.z,w3.w};
    float4 bias = *(const float4*)(cb + d);
    float a0 = bias.x, a1 = bias.y, a2 = bias.z, a3 = bias.w;

    #pragma unroll
    for (int j = 0; j < DC; ++j) {
        int tt = l - (DC-1) + j;
        if (tt < 0) continue;
        float4 xv = *(const float4*)(xz + (size_t)(m - l + tt)*(2*DI) + d);
        a0 = fmaf(wr0[j], xv.x, a0);
        a1 = fmaf(wr1[j], xv.y, a1);
        a2 = fmaf(wr2[j], xv.z, a2);
        a3 = fmaf(wr3[j], xv.w, a3);
    }
    float4 o = { siluf(a0), siluf(a1), siluf(a2), siluf(a3) };
    *(float4*)(xc + (size_t)m*DI + d) = o;
}

// ---------------- chunked selective scan ----------------------------------
__global__ __launch_bounds__(256) void scan_p1(const float* __restrict__ delta,
                                               const float* __restrict__ xc,
                                               const float* __restrict__ dbl,
                                               const float* __restrict__ A_log,
                                               float* __restrict__ Pbuf,
                                               float* __restrict__ Hbuf)
{
    __shared__ float Bsh[CL][16];
    int t = threadIdx.x;
    int blk = blockIdx.x;
    int d = (blk & 7) * 256 + t;
    int c = (blk >> 3) & (NC - 1);
    int b = blk >> 7;
    int m0 = b * L_ + c * CL;

    for (int i = t; i < CL*16; i += 256)
        Bsh[i >> 4][i & 15] = dbl[(size_t)(m0 + (i >> 4))*96 + DR + (i & 15)];
    __syncthreads();

    float A[16], h[16];
    #pragma unroll
    for (int j = 0; j < 4; ++j) {
        float4 al = *(const float4*)(A_log + (size_t)d*DS + j*4);
        A[j*4+0] = -__expf(al.x); A[j*4+1] = -__expf(al.y);
        A[j*4+2] = -__expf(al.z); A[j*4+3] = -__expf(al.w);
    }
    #pragma unroll
    for (int n = 0; n < 16; ++n) h[n] = 0.f;
    float S = 0.f;

    #pragma unroll 4
    for (int tt = 0; tt < CL; ++tt) {
        int m = m0 + tt;
        float dv = delta[(size_t)m*DI + d];
        float xv = xc[(size_t)m*DI + d];
        float dx = dv * xv;
        S += dv;
        #pragma unroll
        for (int n = 0; n < 16; ++n) {
            float dA = __expf(dv * A[n]);
            h[n] = fmaf(dA, h[n], Bsh[tt][n] * dx);
        }
    }

    size_t o = ((size_t)((b*NC + c)*DI) + d) * DS;
    #pragma unroll
    for (int j = 0; j < 4; ++j) {
        float4 pv, hv;
        pv.x = __expf(A[j*4+0]*S); pv.y = __expf(A[j*4+1]*S);
        pv.z = __expf(A[j*4+2]*S); pv.w = __expf(A[j*4+3]*S);
        hv.x = h[j*4+0]; hv.y = h[j*4+1]; hv.z = h[j*4+2]; hv.w = h[j*4+3];
        *(float4*)(Pbuf + o + j*4) = pv;
        *(float4*)(Hbuf + o + j*4) = hv;
    }
}

__global__ __launch_bounds__(256) void scan_p2(float* Pbuf, const float* __restrict__ Hbuf)
{
    int idx = blockIdx.x * 256 + threadIdx.x;
    int n = idx & 15;
    int d = (idx >> 4) & (DI - 1);
    int b = idx >> 15;
    float h = 0.f;
    #pragma unroll
    for (int c = 0; c < NC; ++c) {
        size_t o = ((size_t)((b*NC + c)*DI) + d) * DS + n;
        float p  = Pbuf[o];
        float hh = Hbuf[o];
        Pbuf[o] = h;
        h = fmaf(p, h, hh);
    }
}

// Phase 3: replay chunk, emit g = (y + xc*D)*silu(z) as split bf16 (gh, gl)
__global__ __launch_bounds__(256) void scan_p3(const float* __restrict__ delta,
                                               const float* __restrict__ xz,
                                               const float* __restrict__ xc,
                                               const float* __restrict__ dbl,
                                               const float* __restrict__ A_log,
                                               const float* __restrict__ Dp,
                                               const float* __restrict__ h0buf,
                                               bf16_t* __restrict__ gh,
                                               bf16_t* __restrict__ gl)
{
    __shared__ float Bsh[CL][16];
    __shared__ float Csh[CL][16];
    int t = threadIdx.x;
    int blk = blockIdx.x;
    int d = (blk & 7) * 256 + t;
    int c = (blk >> 3) & (NC - 1);
    int b = blk >> 7;
    int m0 = b * L_ + c * CL;

    for (int i = t; i < CL*16; i += 256) {
        int tt = i >> 4, n = i & 15;
        size_t ro = (size_t)(m0 + tt)*96 + DR;
        Bsh[tt][n] = dbl[ro + n];
        Csh[tt][n] = dbl[ro + DS + n];
    }
    __syncthreads();

    float A[16], h[16];
    #pragma unroll
    for (int j = 0; j < 4; ++j) {
        float4 al = *(const float4*)(A_log + (size_t)d*DS + j*4);
        A[j*4+0] = -__expf(al.x); A[j*4+1] = -__expf(al.y);
        A[j*4+2] = -__expf(al.z); A[j*4+3] = -__expf(al.w);
    }
    size_t o = ((size_t)((b*NC + c)*DI) + d) * DS;
    #pragma unroll
    for (int j = 0; j < 4; ++j) {
        float4 hv = *(const float4*)(h0buf + o + j*4);
        h[j*4+0] = hv.x; h[j*4+1] = hv.y; h[j*4+2] = hv.z; h[j*4+3] = hv.w;
    }
    float Dreg = Dp[d];

    for (int t0 = 0; t0 < CL; t0 += 4) {
        float dv[4], xv[4], zv[4];
        #pragma unroll
        for (int q = 0; q < 4; ++q) {
            int m = m0 + t0 + q;
            dv[q] = delta[(size_t)m*DI + d];
            xv[q] = xc[(size_t)m*DI + d];
            zv[q] = xz[(size_t)m*(2*DI) + DI + d];
        }
        #pragma unroll
        for (int q = 0; q < 4; ++q) {
            int tt = t0 + q, m = m0 + tt;
            float dx = dv[q] * xv[q];
            float y = 0.f;
            #pragma unroll
            for (int n = 0; n < 16; ++n) {
                float dA = __expf(dv[q] * A[n]);
                h[n] = fmaf(dA, h[n], Bsh[tt][n] * dx);
                y = fmaf(h[n], Csh[tt][n], y);
            }
            float gv = (y + xv[q]*Dreg) * siluf(zv[q]);
            bf16_t hh = (bf16_t)gv;
            gh[(size_t)m*DI + d] = hh;
            gl[(size_t)m*DI + d] = (bf16_t)(gv - (float)hh);
        }
    }
}

extern "C" void kernel_launch(void* const* d_in, const int* in_sizes, int n_in,
                              void* d_out, int out_size, void* d_ws, size_t ws_size,
                              hipStream_t stream)
{
    const float* x         = (const float*)d_in[0];
    const float* norm_w    = (const float*)d_in[1];
    const float* in_proj_w = (const float*)d_in[2];
    const float* conv_w    = (const float*)d_in[3];
    const float* conv_b    = (const float*)d_in[4];
    const float* x_proj_w  = (const float*)d_in[5];
    const float* dt_proj_w = (const float*)d_in[6];
    const float* dt_proj_b = (const float*)d_in[7];
    const float* A_log     = (const float*)d_in[8];
    const float* Dp        = (const float*)d_in[9];
    const float* out_proj_w= (const float*)d_in[10];
    float* out = (float*)d_out;

    char* p = (char*)d_ws;
    float* xz    = (float*)p; p += (size_t)NTOK*2*DI*4;    // 33.55 MB
    float* xc    = (float*)p; p += (size_t)NTOK*DI*4;      // 16.78 MB
    float* delta = (float*)p; p += (size_t)NTOK*DI*4;      // 16.78 MB (later: woh/wol)
    float* dbl   = (float*)p; p += (size_t)NTOK*96*4;      //  0.79 MB
    float* Hbuf  = (float*)p; p += (size_t)B_*NC*DI*DS*4;  //  8.39 MB
    float* Pbuf  = (float*)p; p += (size_t)B_*NC*DI*DS*4;  //  8.39 MB (also uh/ul)
    char*  Wreg  = p;         p += (size_t)2*DI*DM*2*2;    // 16.78 MB (wih/wil, later gh/gl)

    bf16_t* uh  = (bf16_t*)Pbuf;                 // 4.19 MB
    bf16_t* ul  = uh + (size_t)NTOK*DM;          // 4.19 MB  (total = Pbuf size)
    bf16_t* wih = (bf16_t*)Wreg;
    bf16_t* wil = wih + (size_t)2*DI*DM;
    bf16_t* gh  = (bf16_t*)Wreg;                 // reuse after in_proj done
    bf16_t* gl  = gh + (size_t)NTOK*DI;
    bf16_t* woh = (bf16_t*)delta;                // reuse after scan_p3 done
    bf16_t* wol = woh + (size_t)DM*DI;

    // 1. RMSNorm -> split bf16 u
    rmsnorm_k<<<NTOK, 256, 0, stream>>>(x, norm_w, uh, ul);

    // 1b. split in_proj_w
    split_k<<<(2*DI*DM/4)/256, 256, 0, stream>>>(in_proj_w, wih, wil, 2*DI*DM/4);

    // 2. in_proj (MFMA): xz[2048,4096] = u @ in_proj_w^T
    gemm_mfma<128,0><<<dim3((2*DI)/128, NTOK/128), 256, 0, stream>>>(
        uh, ul, wih, wil, xz, 2*DI, nullptr, NTOK, 2*DI, DM);

    // 3. causal depthwise conv + SiLU
    conv_silu_k<<<(NTOK*(DI/4))/256, 256, 0, stream>>>(xz, conv_w, conv_b, xc);

    // 4. x_proj: dbl[2048, 96] = xc @ x_proj_w^T   (fp32)
    gemm_nt<0><<<dim3(2, NTOK/64), 256, 0, stream>>>(
        xc, DI, x_proj_w, DI, dbl, 96, NTOK, 96, DI, nullptr, nullptr);

    // 5. dt_proj + softplus (fp32, K=64)
    gemm_big<128,1><<<dim3(DI/128, NTOK/128), 256, 0, stream>>>(
        dbl, 96, dt_proj_w, DR, delta, DI, NTOK, DI, DR, dt_proj_b, nullptr);

    // 6. chunked selective scan; p3 emits split-bf16 g
    scan_p1<<<B_*NC*(DI/256), 256, 0, stream>>>(delta, xc, dbl, A_log, Pbuf, Hbuf);
    scan_p2<<<(B_*DI*DS)/256, 256, 0, stream>>>(Pbuf, Hbuf);
    scan_p3<<<B_*NC*(DI/256), 256, 0, stream>>>(delta, xz, xc, dbl, A_log, Dp,
                                                Pbuf, gh, gl);

    // 6b. split out_proj_w (delta is dead now)
    split_k<<<(DM*DI/4)/256, 256, 0, stream>>>(out_proj_w, woh, wol, DM*DI/4);

    // 7. out_proj (MFMA) + residual: out = g @ out_proj_w^T + x
    gemm_mfma<64,2><<<dim3(DM/64, NTOK/128), 256, 0, stream>>>(
        gh, gl, woh, wol, out, DM, x, NTOK, DM, DI);
}

// Round 4
// 350.530 us; speedup vs baseline: 3.8240x; 1.5498x over previous
//
#include <hip/hip_runtime.h>
#include <math.h>

#define B_   2
#define L_   1024
#define DM   1024
#define DS   16
#define DC   4
#define DI   2048          // E*DM
#define DR   64            // DM/16
#define NTOK (B_*L_)       // 2048
#define EPSF 1e-5f
#define NC   16            // scan chunks
#define CL   (L_/NC)       // 64 steps per chunk
#define SPLITS 8           // x_proj K-splits

typedef __bf16 bf16_t;
typedef bf16_t bf16x4 __attribute__((ext_vector_type(4)));
typedef bf16_t bf16x8 __attribute__((ext_vector_type(8)));
typedef float  f32x4  __attribute__((ext_vector_type(4)));

__device__ __forceinline__ float siluf(float x){ return x / (1.f + __expf(-x)); }
__device__ __forceinline__ float softplusf(float x){ return (x > 20.f) ? x : log1pf(__expf(x)); }

__device__ __forceinline__ void gload_lds16(const void* g, void* l) {
    __builtin_amdgcn_global_load_lds(
        (const __attribute__((address_space(1))) void*)g,
        (__attribute__((address_space(3))) void*)l, 16, 0, 0);
}

// ---------------- RMSNorm -> split bf16 (hi, lo) ---------------------------
__global__ __launch_bounds__(256) void rmsnorm_k(const float* __restrict__ x,
                                                 const float* __restrict__ w,
                                                 bf16_t* __restrict__ uh,
                                                 bf16_t* __restrict__ ul)
{
    int row = blockIdx.x;
    int t = threadIdx.x;
    float4 v = ((const float4*)(x + (size_t)row*DM))[t];
    float ss = v.x*v.x + v.y*v.y + v.z*v.z + v.w*v.w;
    #pragma unroll
    for (int off = 32; off > 0; off >>= 1) ss += __shfl_xor(ss, off, 64);
    __shared__ float sred[4];
    if ((t & 63) == 0) sred[t >> 6] = ss;
    __syncthreads();
    ss = sred[0] + sred[1] + sred[2] + sred[3];
    float rs = rsqrtf(ss * (1.f/(float)DM) + EPSF);
    float4 wv = ((const float4*)w)[t];
    float o[4];
    o[0] = v.x*rs*wv.x; o[1] = v.y*rs*wv.y; o[2] = v.z*rs*wv.z; o[3] = v.w*rs*wv.w;
    bf16x4 hv, lv;
    #pragma unroll
    for (int j = 0; j < 4; ++j) {
        bf16_t h = (bf16_t)o[j];
        hv[j] = h;
        lv[j] = (bf16_t)(o[j] - (float)h);
    }
    *(bf16x4*)(uh + (size_t)row*DM + t*4) = hv;
    *(bf16x4*)(ul + (size_t)row*DM + t*4) = lv;
}

// ---------------- fp32 -> split bf16 (hi, lo) ------------------------------
__global__ __launch_bounds__(256) void split_k(const float* __restrict__ s,
                                               bf16_t* __restrict__ h,
                                               bf16_t* __restrict__ l, int n4)
{
    int i = blockIdx.x * 256 + threadIdx.x;
    if (i >= n4) return;
    float4 v = ((const float4*)s)[i];
    float o[4] = {v.x, v.y, v.z, v.w};
    bf16x4 hv, lv;
    #pragma unroll
    for (int j = 0; j < 4; ++j) {
        bf16_t hh = (bf16_t)o[j];
        hv[j] = hh;
        lv[j] = (bf16_t)(o[j] - (float)hh);
    }
    ((bf16x4*)h)[i] = hv;
    ((bf16x4*)l)[i] = lv;
}

// ------- x_proj weight split, padded [96,2048] -> [128,2048] (rows>=96: 0) --
__global__ __launch_bounds__(256) void splitx_k(const float* __restrict__ s,
                                                bf16_t* __restrict__ h,
                                                bf16_t* __restrict__ l)
{
    int i = blockIdx.x * 256 + threadIdx.x;   // over 128*2048/4
    int row = i >> 9;                         // 2048/4 = 512 float4 per row
    bf16x4 hv, lv;
    if (row < 96) {
        float4 v = ((const float4*)s)[i];
        float o[4] = {v.x, v.y, v.z, v.w};
        #pragma unroll
        for (int j = 0; j < 4; ++j) {
            bf16_t hh = (bf16_t)o[j];
            hv[j] = hh;
            lv[j] = (bf16_t)(o[j] - (float)hh);
        }
    } else {
        #pragma unroll
        for (int j = 0; j < 4; ++j) { hv[j] = (bf16_t)0.f; lv[j] = (bf16_t)0.f; }
    }
    ((bf16x4*)h)[i] = hv;
    ((bf16x4*)l)[i] = lv;
}

// ---------------- split-bf16 MFMA NT GEMM, 2-phase double-buffered ---------
// C[M,N](fp32) = (Ah+Al)[M,K] * (Bh+Bl)[N,K]^T ; 3 MFMAs per fragment pair.
// Tile 128 x BN, 256 threads = 4 waves (2x2).
// EPI: 0 plain, 1 softplus(acc+bias[col]), 2 acc+res[row,col].
// SK: split-K variant — grid.x = split index, n0 = 0, C += split*M*BN.
template<int BN, int EPI, bool SK>
__global__ __launch_bounds__(256) void gemm_mfma(
    const bf16_t* __restrict__ Ah, const bf16_t* __restrict__ Al,
    const bf16_t* __restrict__ Bh, const bf16_t* __restrict__ Bl,
    float* __restrict__ C, int ldc,
    const float* __restrict__ res, const float* __restrict__ bias,
    int M, int N, int K, int kspl)
{
    constexpr int NJ   = BN / 32;        // B fragments per wave (n-dir)
    constexpr int WN   = BN / 2;         // wave n-span
    constexpr int ACH  = 8;              // 1KB chunks per A tile (128x32)
    constexpr int BCH  = BN / 16;        // 1KB chunks per B tile (BNx32)
    constexpr int NCH  = 2*ACH + 2*BCH;
    constexpr int PERW = NCH / 4;
    constexpr int AOFF_L = 128*32;       // elems
    constexpr int BOFF_H = 2*128*32;
    constexpr int BOFF_L = 2*128*32 + BN*32;
    constexpr int BUFSZ  = 2*128*32 + 2*BN*32;

    __shared__ bf16_t lds[2*BUFSZ];

    int t = threadIdx.x;
    int w = t >> 6, lane = t & 63;
    int wr = w >> 1, wc = w & 1;
    int m0 = blockIdx.y * 128;
    int n0 = SK ? 0 : blockIdx.x * BN;
    int k0beg = SK ? blockIdx.x * kspl : 0;
    int nst = (SK ? kspl : K) >> 5;
    float* Cp = C;
    if (SK) Cp += (size_t)blockIdx.x * M * BN;

    f32x4 acc[4][NJ];
    #pragma unroll
    for (int i = 0; i < 4; ++i)
        #pragma unroll
        for (int j = 0; j < NJ; ++j)
            acc[i][j] = (f32x4){0.f, 0.f, 0.f, 0.f};

    int lrow = lane >> 2;          // 0..15 within chunk
    int lcol = (lane & 3) * 8;     // k element offset
    int ar   = wr*64 + (lane & 15);
    int br   = wc*WN + (lane & 15);
    int koff = (lane >> 4) * 8;

    auto STAGE = [&](int buf, int k0) {
        int base = buf ? BUFSZ : 0;
        #pragma unroll
        for (int q = 0; q < PERW; ++q) {
            int ch = w * PERW + q;
            const bf16_t* g; int le;
            if (ch < ACH) {
                int cc = ch;
                g  = Ah + (size_t)(m0 + cc*16 + lrow)*K + k0 + lcol;
                le = cc*512 + lane*8;
            } else if (ch < 2*ACH) {
                int cc = ch - ACH;
                g  = Al + (size_t)(m0 + cc*16 + lrow)*K + k0 + lcol;
                le = AOFF_L + cc*512 + lane*8;
            } else if (ch < 2*ACH + BCH) {
                int cc = ch - 2*ACH;
                g  = Bh + (size_t)(n0 + cc*16 + lrow)*K + k0 + lcol;
                le = BOFF_H + cc*512 + lane*8;
            } else {
                int cc = ch - 2*ACH - BCH;
                g  = Bl + (size_t)(n0 + cc*16 + lrow)*K + k0 + lcol;
                le = BOFF_L + cc*512 + lane*8;
            }
            gload_lds16(g, &lds[base + le]);
        }
    };

    STAGE(0, k0beg);
    __syncthreads();               // drains vmcnt(0): tile 0 resident
    int cur = 0;
    for (int s = 0; s < nst; ++s) {
        int k0 = k0beg + (s << 5);
        if (s + 1 < nst) STAGE(cur ^ 1, k0 + 32);   // prefetch next tile
        int base = cur ? BUFSZ : 0;

        bf16x8 ah[4], al4[4], bh[NJ], bl4[NJ];
        #pragma unroll
        for (int i = 0; i < 4; ++i) {
            ah[i]  = *(const bf16x8*)&lds[base + (ar + i*16)*32 + koff];
            al4[i] = *(const bf16x8*)&lds[base + AOFF_L + (ar + i*16)*32 + koff];
        }
        #pragma unroll
        for (int j = 0; j < NJ; ++j) {
            bh[j]  = *(const bf16x8*)&lds[base + BOFF_H + (br + j*16)*32 + koff];
            bl4[j] = *(const bf16x8*)&lds[base + BOFF_L + (br + j*16)*32 + koff];
        }
        #pragma unroll
        for (int i = 0; i < 4; ++i)
            #pragma unroll
            for (int j = 0; j < NJ; ++j) {
                acc[i][j] = __builtin_amdgcn_mfma_f32_16x16x32_bf16(ah[i],  bh[j],  acc[i][j], 0, 0, 0);
                acc[i][j] = __builtin_amdgcn_mfma_f32_16x16x32_bf16(al4[i], bh[j],  acc[i][j], 0, 0, 0);
                acc[i][j] = __builtin_amdgcn_mfma_f32_16x16x32_bf16(ah[i],  bl4[j], acc[i][j], 0, 0, 0);
            }
        __syncthreads();           // waits vmcnt(0): next tile landed; lgkm: reads done
        cur ^= 1;
    }

    // epilogue: C/D layout col=lane&15, row=(lane>>4)*4+reg  [m89-verified]
    int rb = m0 + wr*64 + (lane >> 4)*4;
    int cb = n0 + wc*WN + (lane & 15);
    #pragma unroll
    for (int i = 0; i < 4; ++i)
        #pragma unroll
        for (int j = 0; j < NJ; ++j) {
            int col = cb + j*16;
            float bcol = (EPI == 1) ? bias[col] : 0.f;
            #pragma unroll
            for (int r = 0; r < 4; ++r) {
                int row = rb + i*16 + r;
                float v = acc[i][j][r];
                if (EPI == 1) v = softplusf(v + bcol);
                if (EPI == 2) v += res[(size_t)row*ldc + col];
                Cp[(size_t)row*ldc + col] = v;
            }
        }
}

// -------- x_proj split-K reduce: sum partials, emit dt(bf16 split) + BC ----
__global__ __launch_bounds__(256) void xproj_reduce(const float* __restrict__ parts,
                                                    bf16_t* __restrict__ dth,
                                                    bf16_t* __restrict__ dtl,
                                                    float* __restrict__ bc)
{
    int idx = blockIdx.x * 256 + threadIdx.x;   // NTOK * 32
    int m  = idx >> 5;
    int c  = (idx & 31) * 4;
    float4 s = {0.f, 0.f, 0.f, 0.f};
    #pragma unroll
    for (int sp = 0; sp < SPLITS; ++sp) {
        float4 v = *(const float4*)(parts + ((size_t)sp*NTOK + m)*128 + c);
        s.x += v.x; s.y += v.y; s.z += v.z; s.w += v.w;
    }
    if (c < 64) {
        float o[4] = {s.x, s.y, s.z, s.w};
        bf16x4 hv, lv;
        #pragma unroll
        for (int j = 0; j < 4; ++j) {
            bf16_t hh = (bf16_t)o[j];
            hv[j] = hh;
            lv[j] = (bf16_t)(o[j] - (float)hh);
        }
        *(bf16x4*)(dth + (size_t)m*DR + c) = hv;
        *(bf16x4*)(dtl + (size_t)m*DR + c) = lv;
    } else if (c < 96) {
        *(float4*)(bc + (size_t)m*32 + (c - 64)) = s;
    }
}

// ------- causal depthwise conv (DC=4) + bias + SiLU -> split bf16 ----------
__global__ __launch_bounds__(256) void conv_silu_k(const float* __restrict__ xz,
                                                   const float* __restrict__ cw,
                                                   const float* __restrict__ cb,
                                                   bf16_t* __restrict__ xch,
                                                   bf16_t* __restrict__ xcl)
{
    int idx = blockIdx.x * 256 + threadIdx.x;
    int d4 = idx & (DI/4 - 1);
    int m  = idx >> 9;
    int l  = m & (L_ - 1);
    int d  = d4 * 4;

    float4 w0 = *(const float4*)(cw + (size_t)(d+0)*DC);
    float4 w1 = *(const float4*)(cw + (size_t)(d+1)*DC);
    float4 w2 = *(const float4*)(cw + (size_t)(d+2)*DC);
    float4 w3 = *(const float4*)(cw + (size_t)(d+3)*DC);
    float wr0[4] = {w0.x,w0.y,w0.z,w0.w};
    float wr1[4] = {w1.x,w1.y,w1.z,w1.w};
    float wr2[4] = {w2.x,w2.y,w2.z,w2.w};
    float wr3[4] = {w3.x,w3.y,w3.z,w3.w};
    float4 bias = *(const float4*)(cb + d);
    float a0 = bias.x, a1 = bias.y, a2 = bias.z, a3 = bias.w;

    #pragma unroll
    for (int j = 0; j < DC; ++j) {
        int tt = l - (DC-1) + j;
        if (tt < 0) continue;
        float4 xv = *(const float4*)(xz + (size_t)(m - l + tt)*(2*DI) + d);
        a0 = fmaf(wr0[j], xv.x, a0);
        a1 = fmaf(wr1[j], xv.y, a1);
        a2 = fmaf(wr2[j], xv.z, a2);
        a3 = fmaf(wr3[j], xv.w, a3);
    }
    float o[4] = { siluf(a0), siluf(a1), siluf(a2), siluf(a3) };
    bf16x4 hv, lv;
    #pragma unroll
    for (int j = 0; j < 4; ++j) {
        bf16_t hh = (bf16_t)o[j];
        hv[j] = hh;
        lv[j] = (bf16_t)(o[j] - (float)hh);
    }
    *(bf16x4*)(xch + (size_t)m*DI + d) = hv;
    *(bf16x4*)(xcl + (size_t)m*DI + d) = lv;
}

// ---------------- chunked selective scan ----------------------------------
__global__ __launch_bounds__(256) void scan_p1(const float* __restrict__ delta,
                                               const bf16_t* __restrict__ xch,
                                               const bf16_t* __restrict__ xcl,
                                               const float* __restrict__ bc,
                                               const float* __restrict__ A_log,
                                               float* __restrict__ Pbuf,
                                               float* __restrict__ Hbuf)
{
    __shared__ float Bsh[CL][16];
    int t = threadIdx.x;
    int blk = blockIdx.x;
    int d = (blk & 7) * 256 + t;
    int c = (blk >> 3) & (NC - 1);
    int b = blk >> 7;
    int m0 = b * L_ + c * CL;

    for (int i = t; i < CL*16; i += 256)
        Bsh[i >> 4][i & 15] = bc[(size_t)(m0 + (i >> 4))*32 + (i & 15)];
    __syncthreads();

    float A[16], h[16];
    #pragma unroll
    for (int j = 0; j < 4; ++j) {
        float4 al = *(const float4*)(A_log + (size_t)d*DS + j*4);
        A[j*4+0] = -__expf(al.x); A[j*4+1] = -__expf(al.y);
        A[j*4+2] = -__expf(al.z); A[j*4+3] = -__expf(al.w);
    }
    #pragma unroll
    for (int n = 0; n < 16; ++n) h[n] = 0.f;
    float S = 0.f;

    #pragma unroll 4
    for (int tt = 0; tt < CL; ++tt) {
        int m = m0 + tt;
        float dv = delta[(size_t)m*DI + d];
        float xv = (float)xch[(size_t)m*DI + d] + (float)xcl[(size_t)m*DI + d];
        float dx = dv * xv;
        S += dv;
        #pragma unroll
        for (int n = 0; n < 16; ++n) {
            float dA = __expf(dv * A[n]);
            h[n] = fmaf(dA, h[n], Bsh[tt][n] * dx);
        }
    }

    size_t o = ((size_t)((b*NC + c)*DI) + d) * DS;
    #pragma unroll
    for (int j = 0; j < 4; ++j) {
        float4 pv, hv;
        pv.x = __expf(A[j*4+0]*S); pv.y = __expf(A[j*4+1]*S);
        pv.z = __expf(A[j*4+2]*S); pv.w = __expf(A[j*4+3]*S);
        hv.x = h[j*4+0]; hv.y = h[j*4+1]; hv.z = h[j*4+2]; hv.w = h[j*4+3];
        *(float4*)(Pbuf + o + j*4) = pv;
        *(float4*)(Hbuf + o + j*4) = hv;
    }
}

__global__ __launch_bounds__(256) void scan_p2(float* Pbuf, const float* __restrict__ Hbuf)
{
    int idx = blockIdx.x * 256 + threadIdx.x;
    int n = idx & 15;
    int d = (idx >> 4) & (DI - 1);
    int b = idx >> 15;
    float h = 0.f;
    #pragma unroll
    for (int c = 0; c < NC; ++c) {
        size_t o = ((size_t)((b*NC + c)*DI) + d) * DS + n;
        float p  = Pbuf[o];
        float hh = Hbuf[o];
        Pbuf[o] = h;
        h = fmaf(p, h, hh);
    }
}

// Phase 3: replay chunk, emit g = (y + xc*D)*silu(z) as split bf16 (gh, gl)
__global__ __launch_bounds__(256) void scan_p3(const float* __restrict__ delta,
                                               const float* __restrict__ xz,
                                               const bf16_t* __restrict__ xch,
                                               const bf16_t* __restrict__ xcl,
                                               const float* __restrict__ bc,
                                               const float* __restrict__ A_log,
                                               const float* __restrict__ Dp,
                                               const float* __restrict__ h0buf,
                                               bf16_t* __restrict__ gh,
                                               bf16_t* __restrict__ gl)
{
    __shared__ float Bsh[CL][16];
    __shared__ float Csh[CL][16];
    int t = threadIdx.x;
    int blk = blockIdx.x;
    int d = (blk & 7) * 256 + t;
    int c = (blk >> 3) & (NC - 1);
    int b = blk >> 7;
    int m0 = b * L_ + c * CL;

    for (int i = t; i < CL*16; i += 256) {
        int tt = i >> 4, n = i & 15;
        size_t ro = (size_t)(m0 + tt)*32;
        Bsh[tt][n] = bc[ro + n];
        Csh[tt][n] = bc[ro + 16 + n];
    }
    __syncthreads();

    float A[16], h[16];
    #pragma unroll
    for (int j = 0; j < 4; ++j) {
        float4 al = *(const float4*)(A_log + (size_t)d*DS + j*4);
        A[j*4+0] = -__expf(al.x); A[j*4+1] = -__expf(al.y);
        A[j*4+2] = -__expf(al.z); A[j*4+3] = -__expf(al.w);
    }
    size_t o = ((size_t)((b*NC + c)*DI) + d) * DS;
    #pragma unroll
    for (int j = 0; j < 4; ++j) {
        float4 hv = *(const float4*)(h0buf + o + j*4);
        h[j*4+0] = hv.x; h[j*4+1] = hv.y; h[j*4+2] = hv.z; h[j*4+3] = hv.w;
    }
    float Dreg = Dp[d];

    for (int t0 = 0; t0 < CL; t0 += 4) {
        float dv[4], xv[4], zv[4];
        #pragma unroll
        for (int q = 0; q < 4; ++q) {
            int m = m0 + t0 + q;
            dv[q] = delta[(size_t)m*DI + d];
            xv[q] = (float)xch[(size_t)m*DI + d] + (float)xcl[(size_t)m*DI + d];
            zv[q] = xz[(size_t)m*(2*DI) + DI + d];
        }
        #pragma unroll
        for (int q = 0; q < 4; ++q) {
            int tt = t0 + q, m = m0 + tt;
            float dx = dv[q] * xv[q];
            float y = 0.f;
            #pragma unroll
            for (int n = 0; n < 16; ++n) {
                float dA = __expf(dv[q] * A[n]);
                h[n] = fmaf(dA, h[n], Bsh[tt][n] * dx);
                y = fmaf(h[n], Csh[tt][n], y);
            }
            float gv = (y + xv[q]*Dreg) * siluf(zv[q]);
            bf16_t hh = (bf16_t)gv;
            gh[(size_t)m*DI + d] = hh;
            gl[(size_t)m*DI + d] = (bf16_t)(gv - (float)hh);
        }
    }
}

extern "C" void kernel_launch(void* const* d_in, const int* in_sizes, int n_in,
                              void* d_out, int out_size, void* d_ws, size_t ws_size,
                              hipStream_t stream)
{
    const float* x         = (const float*)d_in[0];
    const float* norm_w    = (const float*)d_in[1];
    const float* in_proj_w = (const float*)d_in[2];
    const float* conv_w    = (const float*)d_in[3];
    const float* conv_b    = (const float*)d_in[4];
    const float* x_proj_w  = (const float*)d_in[5];
    const float* dt_proj_w = (const float*)d_in[6];
    const float* dt_proj_b = (const float*)d_in[7];
    const float* A_log     = (const float*)d_in[8];
    const float* Dp        = (const float*)d_in[9];
    const float* out_proj_w= (const float*)d_in[10];
    float* out = (float*)d_out;

    char* p = (char*)d_ws;
    float*  xz    = (float*)p;  p += (size_t)NTOK*2*DI*4;    // 33.55 MB
    bf16_t* xch   = (bf16_t*)p; p += (size_t)NTOK*DI*2;      //  8.39 MB
    bf16_t* xcl   = (bf16_t*)p; p += (size_t)NTOK*DI*2;      //  8.39 MB
    float*  delta = (float*)p;  p += (size_t)NTOK*DI*4;      // 16.78 MB (later woh/wol)
    float*  bc    = (float*)p;  p += (size_t)NTOK*32*4;      //  0.26 MB
    bf16_t* dth   = (bf16_t*)p; p += (size_t)NTOK*DR*2;      //  0.26 MB
    bf16_t* dtl   = (bf16_t*)p; p += (size_t)NTOK*DR*2;      //  0.26 MB
    float*  Hbuf  = (float*)p;  p += (size_t)B_*NC*DI*DS*4;  //  8.39 MB (also parts)
    float*  Pbuf  = (float*)p;  p += (size_t)B_*NC*DI*DS*4;  //  8.39 MB (also uh/ul)
    char*   Wreg  = p;          p += (size_t)2*DI*DM*2*2;    // 16.78 MB (wih/wil -> gh/gl)
    bf16_t* wxh   = (bf16_t*)p; p += (size_t)128*DI*2;       //  0.52 MB
    bf16_t* wxl   = (bf16_t*)p; p += (size_t)128*DI*2;       //  0.52 MB
    bf16_t* wdth  = (bf16_t*)p; p += (size_t)DI*DR*2;        //  0.26 MB
    bf16_t* wdtl  = (bf16_t*)p; p += (size_t)DI*DR*2;        //  0.26 MB

    bf16_t* uh  = (bf16_t*)Pbuf;                 // dead before scan_p1 writes Pbuf
    bf16_t* ul  = uh + (size_t)NTOK*DM;
    bf16_t* wih = (bf16_t*)Wreg;
    bf16_t* wil = wih + (size_t)2*DI*DM;
    bf16_t* gh  = (bf16_t*)Wreg;                 // reuse after in_proj done
    bf16_t* gl  = gh + (size_t)NTOK*DI;
    bf16_t* woh = (bf16_t*)delta;                // reuse after scan_p3 done
    bf16_t* wol = woh + (size_t)DM*DI;
    float*  parts = Hbuf;                        // dead before scan_p1 writes Hbuf

    // 1. RMSNorm -> split bf16 u
    rmsnorm_k<<<NTOK, 256, 0, stream>>>(x, norm_w, uh, ul);

    // 1b. weight splits
    split_k<<<(2*DI*DM/4)/256, 256, 0, stream>>>(in_proj_w, wih, wil, 2*DI*DM/4);
    split_k<<<(DI*DR/4)/256, 256, 0, stream>>>(dt_proj_w, wdth, wdtl, DI*DR/4);
    splitx_k<<<(128*DI/4)/256, 256, 0, stream>>>(x_proj_w, wxh, wxl);

    // 2. in_proj (MFMA): xz[2048,4096] = u @ in_proj_w^T
    gemm_mfma<128,0,false><<<dim3((2*DI)/128, NTOK/128), 256, 0, stream>>>(
        uh, ul, wih, wil, xz, 2*DI, nullptr, nullptr, NTOK, 2*DI, DM, 0);

    // 3. causal depthwise conv + SiLU -> split bf16 xc
    conv_silu_k<<<(NTOK*(DI/4))/256, 256, 0, stream>>>(xz, conv_w, conv_b, xch, xcl);

    // 4. x_proj (MFMA, split-K over K=2048): parts[8][2048][128]
    gemm_mfma<128,0,true><<<dim3(SPLITS, NTOK/128), 256, 0, stream>>>(
        xch, xcl, wxh, wxl, parts, 128, nullptr, nullptr, NTOK, 128, DI, DI/SPLITS);
    xproj_reduce<<<(NTOK*32)/256, 256, 0, stream>>>(parts, dth, dtl, bc);

    // 5. dt_proj (MFMA, K=64) + softplus + bias -> delta fp32
    gemm_mfma<128,1,false><<<dim3(DI/128, NTOK/128), 256, 0, stream>>>(
        dth, dtl, wdth, wdtl, delta, DI, nullptr, dt_proj_b, NTOK, DI, DR, 0);

    // 6. chunked selective scan; p3 emits split-bf16 g
    scan_p1<<<B_*NC*(DI/256), 256, 0, stream>>>(delta, xch, xcl, bc, A_log, Pbuf, Hbuf);
    scan_p2<<<(B_*DI*DS)/256, 256, 0, stream>>>(Pbuf, Hbuf);
    scan_p3<<<B_*NC*(DI/256), 256, 0, stream>>>(delta, xz, xch, xcl, bc, A_log, Dp,
                                                Pbuf, gh, gl);

    // 6b. split out_proj_w (delta is dead now)
    split_k<<<(DM*DI/4)/256, 256, 0, stream>>>(out_proj_w, woh, wol, DM*DI/4);

    // 7. out_proj (MFMA) + residual: out = g @ out_proj_w^T + x
    gemm_mfma<64,2,false><<<dim3(DM/64, NTOK/128), 256, 0, stream>>>(
        gh, gl, woh, wol, out, DM, x, nullptr, NTOK, DM, DI, 0);
}